// Round 7
// baseline (1050.604 us; speedup 1.0000x reference)
//
#include <hip/hip_runtime.h>
#include <hip/hip_bf16.h>
#include <math.h>

typedef __attribute__((ext_vector_type(8))) short short8;
typedef __attribute__((ext_vector_type(4))) float f32x4;

// B=4096, S=64, V=50000, D=300, H=6, E=400, VS=200, DH=50

// ws layout (ushort elems): MFMA B-frag tiles, 512 elems each:
// elem(lane,i) = W[k][n], n = tn*16+(lane&15), k = kt*32+(lane>>4)*8+i
#define QF 0        // [20 tn][10 kt][512]  Wq + aug cols n=300..305 (cq_h)
#define KF 102400   // [19][10][512]  Wk
#define VF 199680   // [19][10][512]  Wv
#define OFC 296960  // [19 tn][20 kt][512]  fused [Wo ; Wro] (kt<10: Wo, kt>=10: Wr@Wo)
#define PFW 491520  // [25][10][512]  Wp
#define AFW 619520  // [13][13][512]  Wa
#define BOBF 706048 // float[304] at elem BOBF (byte 2*BOBF): bias bo + br@Wo
#define PREP_TOTAL (706048 + 608)

__device__ __forceinline__ unsigned short f2b(float f) {
  unsigned int u = __builtin_bit_cast(unsigned int, f);
  u += 0x7FFFu + ((u >> 16) & 1u);
  return (unsigned short)(u >> 16);
}
__device__ __forceinline__ float b2f(unsigned short h) {
  unsigned int u = ((unsigned int)h) << 16;
  return __builtin_bit_cast(float, u);
}

__global__ void prep_weights(const float* __restrict__ Wq, const float* __restrict__ Wk,
                             const float* __restrict__ Wv, const float* __restrict__ Wr,
                             const float* __restrict__ Wo, const float* __restrict__ Wp,
                             const float* __restrict__ Wa, const float* __restrict__ wq_attn,
                             const float* __restrict__ br, const float* __restrict__ bo,
                             unsigned short* __restrict__ ws) {
  int idx = blockIdx.x * blockDim.x + threadIdx.x;
  if (idx >= PREP_TOTAL) return;
  if (idx >= BOBF) {                      // fused attn-out bias (fp32)
    int n = idx - BOBF;                   // 0..607
    if (n >= 304) return;
    float s = 0.f;
    if (n < 300) {
      s = bo[n];
      for (int m = 0; m < 300; ++m) s += br[m % 50] * Wo[m * 300 + n];
    }
    ((float*)(ws))[BOBF / 2 + n] = s;
    return;
  }
  float val = 0.f;
  if (idx < KF) {                         // Q' = [Wq | cq_h]
    int tn = idx / 5120, r = idx % 5120;
    int kt = r / 512; r &= 511;
    int lane = r >> 3, i = r & 7;
    int n = tn * 16 + (lane & 15), k = kt * 32 + (lane >> 4) * 8 + i;
    if (k < 300) {
      if (n < 300) val = Wq[k * 300 + n];
      else if (n < 306) {
        int h = n - 300;
        float s = 0.f;
        for (int d = 0; d < 50; ++d) s += Wq[k * 300 + 50 * h + d] * wq_attn[h * 50 + d];
        val = s;
      }
    }
  } else if (idx < OFC) {                 // Wk / Wv (plain 300x300)
    int m = (idx - KF) / 97280;
    int local = (idx - KF) % 97280;
    int tn = local / 5120, r = local % 5120;
    int kt = r / 512; r &= 511;
    int lane = r >> 3, i = r & 7;
    int n = tn * 16 + (lane & 15), k = kt * 32 + (lane >> 4) * 8 + i;
    if (n < 300 && k < 300) {
      const float* W = (m == 0) ? Wk : Wv;
      val = W[k * 300 + n];
    }
  } else if (idx < PFW) {                 // fused [Wo ; Wro], 20 kt
    int local = idx - OFC;
    int tn = local / 10240, r = local % 10240;
    int kt = r / 512; r &= 511;
    int lane = r >> 3, i = r & 7;
    int n = tn * 16 + (lane & 15), kk = (lane >> 4) * 8 + i;
    if (n < 300) {
      if (kt < 10) {
        int k = kt * 32 + kk;
        if (k < 300) val = Wo[k * 300 + n];
      } else {
        int k = (kt - 10) * 32 + kk;
        if (k < 300) {                    // Wro[k][n] = sum_j Wr[k%50][j] Wo[50*(k/50)+j][n]
          int h = k / 50, i2 = k % 50;
          float s = 0.f;
          for (int j = 0; j < 50; ++j) s += Wr[i2 * 50 + j] * Wo[(50 * h + j) * 300 + n];
          val = s;
        }
      }
    }
  } else if (idx < AFW) {                 // Wp [300][400]
    int local = idx - PFW;
    int tn = local / 5120, r = local % 5120;
    int kt = r / 512; r &= 511;
    int lane = r >> 3, i = r & 7;
    int n = tn * 16 + (lane & 15), k = kt * 32 + (lane >> 4) * 8 + i;
    if (k < 300) val = Wp[k * 400 + n];
  } else {                                // Wa [400][200], 13 kt
    int local = idx - AFW;
    int tn = local / 6656, r = local % 6656;
    int kt = r / 512; r &= 511;
    int lane = r >> 3, i = r & 7;
    int n = tn * 16 + (lane & 15), k = kt * 32 + (lane >> 4) * 8 + i;
    if (n < 200 && k < 400) val = Wa[k * 200 + n];
  }
  ws[idx] = f2b(val);
}

// LDS layout (bytes), total 162624 <= 163840
#define MISC_OFF 0      // float[704]: aM[6][64] gkf[320]; overlay scp[4][64]+wsm[64]
#define XB 2816         // ushort [64][312]  x -> u
#define QB 42752        // ushort [64][312]  q   (hb overlays QB.. in phase E)
#define KB 82688        // ushort [64][312]  K
#define VB 122624       // ushort [64][312]  v -> attn_out
#define PAD_OFF 162560  // 64 B zeroed tail pad (vb row-63 kt=9 over-read target)
#define SMEM_BYTES 162624
#define STR 312
#define HSTR 408        // hb [64][408] at QB (52224 B, ends 94976; overlays qb + kb head)

template <int KT>
__device__ __forceinline__ void loadBT(short8* b, const unsigned short* p) {
#pragma unroll
  for (int kt = 0; kt < KT; ++kt) b[kt] = *(const short8*)(p + kt * 512);
}

__global__ __launch_bounds__(1024) __attribute__((amdgpu_waves_per_eu(4, 4)))
void doc_encoder(
    const int* __restrict__ tokens, const float* __restrict__ emb,
    const float* __restrict__ wk_attn, const float* __restrict__ bp_,
    const float* __restrict__ ba_, const float* __restrict__ va_,
    const unsigned short* __restrict__ ws, float* __restrict__ out) {
  __shared__ alignas(16) unsigned char smem[SMEM_BYTES];
  float* miscf = (float*)(smem + MISC_OFF);
  unsigned short* xb = (unsigned short*)(smem + XB);
  unsigned short* qb = (unsigned short*)(smem + QB);
  unsigned short* kb = (unsigned short*)(smem + KB);
  unsigned short* vb = (unsigned short*)(smem + VB);
  unsigned short* hb = (unsigned short*)(smem + QB);   // overlay
  unsigned short* pad = (unsigned short*)(smem + PAD_OFF);
  float* gkf = miscf + 384;   // [320]
  float* scp = miscf;         // [4][64] overlay aM (dead by phase F)
  float* wsm = miscf + 512;   // [64]

  const int b = blockIdx.x;
  const int tid = threadIdx.x;
  const int lane = tid & 63;
  const int wv = tid >> 6;       // 0..15
  const int wm4 = wv & 3;        // M tile (rows wm4*16 .. +15)
  const int w4 = wv >> 2;        // 4-way N split
  const int l15 = lane & 15;
  const int lg = lane >> 4;
  const int kofs = lg * 8;
  const int arow = wm4 * 16 + l15;
  const int cr0 = wm4 * 16 + lg * 4;
  const float* bobf = (const float*)(ws + BOBF);

  // ---- zero pads: qb/kb/vb cols 300..311, gkf tail, smem tail pad,
  //      qb row-0 head (xb row-63 kt=9 over-read target during phase B) ----
  for (int i = tid; i < 64 * 12; i += 1024) {
    int s = i / 12, c = 300 + i % 12;
    qb[s * STR + c] = 0; kb[s * STR + c] = 0; vb[s * STR + c] = 0;
  }
  if (tid < 20) gkf[300 + tid] = 0.f;
  if (tid < 32) pad[tid] = 0;
  if (tid < 8) qb[tid] = 0;

  // ---- gather x = emb[tokens[b]] -> bf16 xb [64][312] ----
  for (int i = tid; i < 64 * 39; i += 1024) {
    int s = i / 39, c8 = (i % 39) * 8;
    int tok = tokens[b * 64 + s];
    const float* rp = emb + (size_t)tok * 300;
    short8 v;
    if (c8 + 8 <= 300) {
      f32x4 u0 = *(const f32x4*)(rp + c8);
      f32x4 u1 = *(const f32x4*)(rp + c8 + 4);
#pragma unroll
      for (int j = 0; j < 4; ++j) { v[j] = (short)f2b(u0[j]); v[4 + j] = (short)f2b(u1[j]); }
    } else {
#pragma unroll
      for (int j = 0; j < 8; ++j) v[j] = (c8 + j < 300) ? (short)f2b(rp[c8 + j]) : (short)0;
    }
    *(short8*)&xb[s * STR + c8] = v;
  }
  __syncthreads();   // B0

  const float scale = 0.1414213562373095f;  // 50^-0.5

  // ---- Phase B: Q'(20) K(19) V(19) = 58 jobs, stride 4; A resident (1 tile) ----
  {
    short8 ax[10];
#pragma unroll
    for (int kt = 0; kt < 10; ++kt)
      ax[kt] = *(const short8*)&xb[arow * STR + kt * 32 + kofs];

    for (int j = w4; j < 58; j += 4) {
      const unsigned short* wb;
      if (j < 20) wb = ws + QF + (size_t)j * 5120 + lane * 8;
      else if (j < 39) wb = ws + KF + (size_t)(j - 20) * 5120 + lane * 8;
      else wb = ws + VF + (size_t)(j - 39) * 5120 + lane * 8;
      short8 bt[10];
      loadBT<10>(bt, wb);
      f32x4 c0 = {0.f, 0.f, 0.f, 0.f}, c1 = c0;
#pragma unroll
      for (int k = 0; k < 10; k += 2) {
        c0 = __builtin_amdgcn_mfma_f32_16x16x32_bf16(ax[k], bt[k], c0, 0, 0, 0);
        c1 = __builtin_amdgcn_mfma_f32_16x16x32_bf16(ax[k + 1], bt[k + 1], c1, 0, 0, 0);
      }
      if (j < 20) {
        int n = j * 16 + l15;
        if (n < 300) {
#pragma unroll
          for (int r = 0; r < 4; ++r) qb[(cr0 + r) * STR + n] = f2b(c0[r] + c1[r]);
        } else if (n < 306) {
          float* aMh = miscf + (n - 300) * 64;
#pragma unroll
          for (int r = 0; r < 4; ++r) aMh[cr0 + r] = (c0[r] + c1[r]) * scale;
        }
      } else if (j < 39) {
        int n = (j - 20) * 16 + l15;
        if (n < 300) {
#pragma unroll
          for (int r = 0; r < 4; ++r) kb[(cr0 + r) * STR + n] = f2b(c0[r] + c1[r]);
        }
      } else {
        int n = (j - 39) * 16 + l15;
        if (n < 300) {
#pragma unroll
          for (int r = 0; r < 4; ++r) vb[(cr0 + r) * STR + n] = f2b(c0[r] + c1[r]);
        }
      }
    }
  }
  __syncthreads();   // B1

  // ---- Stage C: wave h handles head h entirely in-wave ----
  if (wv < 6) {
    const int h = wv;
    float* aMh = miscf + h * 64;
    float lgt = aMh[lane];
    float m = lgt;
#pragma unroll
    for (int off = 32; off; off >>= 1) m = fmaxf(m, __shfl_xor(m, off));
    float e = __expf(lgt - m);
    float ss = e;
#pragma unroll
    for (int off = 32; off; off >>= 1) ss += __shfl_xor(ss, off);
    aMh[lane] = e / ss;   // alpha
    float g = 0.f;
    if (lane < 50) {
      const unsigned short* qcol = qb + 50 * h + lane;
      for (int s = 0; s < 64; ++s) g += aMh[s] * b2f(qcol[s * STR]);
    }
    float gw = (lane < 50) ? g * wk_attn[h * 50 + lane] : 0.f;
    aMh[lane] = gw;
    float p = 0.f;
    {
      const unsigned short* krow = kb + lane * STR + 50 * h;
      for (int d = 0; d < 50; ++d) p += aMh[d] * b2f(krow[d]);
    }
    p *= scale;
    m = p;
#pragma unroll
    for (int off = 32; off; off >>= 1) m = fmaxf(m, __shfl_xor(m, off));
    e = __expf(p - m);
    ss = e;
#pragma unroll
    for (int off = 32; off; off >>= 1) ss += __shfl_xor(ss, off);
    aMh[lane] = e / ss;   // beta
    if (lane < 50) {
      float gks = 0.f;
      const unsigned short* kcol = kb + 50 * h + lane;
      for (int s = 0; s < 64; ++s) gks += aMh[s] * b2f(kcol[s * STR]);
      gkf[50 * h + lane] = g * gks;
    }
  }
  __syncthreads();   // B2

  // ---- u = gk o v -> xb (x dead), all cols 0..311 defined ----
  for (int i = tid; i < 64 * 39; i += 1024) {
    int s = i / 39, c8 = (i % 39) * 8;
    short8 vf = *(const short8*)&vb[s * STR + c8];
    short8 uf;
#pragma unroll
    for (int j = 0; j < 8; ++j) {
      int c = c8 + j;
      uf[j] = (c < 300) ? (short)f2b(gkf[c] * b2f((unsigned short)vf[j])) : (short)0;
    }
    *(short8*)&xb[s * STR + c8] = uf;
  }
  __syncthreads();   // B3

  // ---- attn_out = q@Wo + u@Wro + bobf -> vb (19 jobs, 2 passes of 10 kt) ----
  {
    short8 aq[10];
#pragma unroll
    for (int kt = 0; kt < 10; ++kt)
      aq[kt] = *(const short8*)&qb[arow * STR + kt * 32 + kofs];
    const unsigned short* aub = xb + arow * STR + kofs;

    for (int t = w4; t < 19; t += 4) {
      short8 bt[10];
      loadBT<10>(bt, ws + OFC + (size_t)t * 10240 + lane * 8);
      f32x4 c0 = {0.f, 0.f, 0.f, 0.f}, c1 = c0;
#pragma unroll
      for (int k = 0; k < 10; k += 2) {
        c0 = __builtin_amdgcn_mfma_f32_16x16x32_bf16(aq[k], bt[k], c0, 0, 0, 0);
        c1 = __builtin_amdgcn_mfma_f32_16x16x32_bf16(aq[k + 1], bt[k + 1], c1, 0, 0, 0);
      }
      loadBT<10>(bt, ws + OFC + (size_t)t * 10240 + 5120 + lane * 8);
#pragma unroll
      for (int k = 0; k < 10; k += 2) {
        short8 a0 = *(const short8*)(aub + k * 32);
        c0 = __builtin_amdgcn_mfma_f32_16x16x32_bf16(a0, bt[k], c0, 0, 0, 0);
        short8 a1 = *(const short8*)(aub + (k + 1) * 32);
        c1 = __builtin_amdgcn_mfma_f32_16x16x32_bf16(a1, bt[k + 1], c1, 0, 0, 0);
      }
      int n = t * 16 + l15;
      if (n < 300) {
        float bias = bobf[n];
#pragma unroll
        for (int r = 0; r < 4; ++r) vb[(cr0 + r) * STR + n] = f2b(c0[r] + c1[r] + bias);
      }
    }
  }
  __syncthreads();   // B4

  // ---- h = attn_out @ Wp + bp -> hb [64][408] (overlays qb + kb head) ----
  {
    short8 av[10];
#pragma unroll
    for (int kt = 0; kt < 10; ++kt)
      av[kt] = *(const short8*)&vb[arow * STR + kt * 32 + kofs];
    for (int t = w4; t < 25; t += 4) {
      short8 bt[10];
      loadBT<10>(bt, ws + PFW + (size_t)t * 5120 + lane * 8);
      f32x4 c0 = {0.f, 0.f, 0.f, 0.f}, c1 = c0;
#pragma unroll
      for (int k = 0; k < 10; k += 2) {
        c0 = __builtin_amdgcn_mfma_f32_16x16x32_bf16(av[k], bt[k], c0, 0, 0, 0);
        c1 = __builtin_amdgcn_mfma_f32_16x16x32_bf16(av[k + 1], bt[k + 1], c1, 0, 0, 0);
      }
      int n = t * 16 + l15;   // < 400
      float bias = bp_[n];
#pragma unroll
      for (int r = 0; r < 4; ++r) hb[(cr0 + r) * HSTR + n] = f2b(c0[r] + c1[r] + bias);
    }
  }
  __syncthreads();   // B5

  // ---- scores = tanh(h@Wa + ba) @ va -> scp ----
  {
    short8 ah[13];
#pragma unroll
    for (int kt = 0; kt < 13; ++kt)
      ah[kt] = *(const short8*)&hb[arow * HSTR + kt * 32 + kofs];
    float sp[4] = {0.f, 0.f, 0.f, 0.f};
    for (int t = w4; t < 13; t += 4) {
      short8 bt[13];
      loadBT<13>(bt, ws + AFW + (size_t)t * 6656 + lane * 8);
      f32x4 c0 = {0.f, 0.f, 0.f, 0.f}, c1 = c0;
#pragma unroll
      for (int k = 0; k < 12; k += 2) {
        c0 = __builtin_amdgcn_mfma_f32_16x16x32_bf16(ah[k], bt[k], c0, 0, 0, 0);
        c1 = __builtin_amdgcn_mfma_f32_16x16x32_bf16(ah[k + 1], bt[k + 1], c1, 0, 0, 0);
      }
      c0 = __builtin_amdgcn_mfma_f32_16x16x32_bf16(ah[12], bt[12], c0, 0, 0, 0);
      int n = t * 16 + l15;
      if (n < 200) {
        float ban = ba_[n], van = va_[n];
#pragma unroll
        for (int r = 0; r < 4; ++r) {
          float x0 = fminf(fmaxf(c0[r] + c1[r] + ban, -15.f), 15.f);
          float t0 = __expf(2.f * x0);
          sp[r] += (t0 - 1.f) / (t0 + 1.f) * van;
        }
      }
    }
#pragma unroll
    for (int off = 1; off < 16; off <<= 1) {
#pragma unroll
      for (int r = 0; r < 4; ++r) sp[r] += __shfl_xor(sp[r], off);
    }
    if (l15 == 0) {
#pragma unroll
      for (int r = 0; r < 4; ++r) scp[w4 * 64 + cr0 + r] = sp[r];
    }
  }
  __syncthreads();   // B6
  if (wv == 0) {
    float x = scp[lane] + scp[64 + lane] + scp[128 + lane] + scp[192 + lane];
    float m = x;
#pragma unroll
    for (int off = 32; off; off >>= 1) m = fmaxf(m, __shfl_xor(m, off));
    float e = __expf(x - m);
    float ss = e;
#pragma unroll
    for (int off = 32; off; off >>= 1) ss += __shfl_xor(ss, off);
    wsm[lane] = e / ss;
  }
  __syncthreads();   // B7

  // ---- pooled[e] = sum_s wsm[s] h[s][e] ----
  if (tid < 400) {
    float a0 = 0.f, a1 = 0.f, a2 = 0.f, a3 = 0.f;
    for (int s = 0; s < 64; s += 4) {
      a0 += wsm[s] * b2f(hb[s * HSTR + tid]);
      a1 += wsm[s + 1] * b2f(hb[(s + 1) * HSTR + tid]);
      a2 += wsm[s + 2] * b2f(hb[(s + 2) * HSTR + tid]);
      a3 += wsm[s + 3] * b2f(hb[(s + 3) * HSTR + tid]);
    }
    out[(size_t)b * 400 + tid] = (a0 + a1) + (a2 + a3);
  }
}

extern "C" void kernel_launch(void* const* d_in, const int* in_sizes, int n_in,
                              void* d_out, int out_size, void* d_ws, size_t ws_size,
                              hipStream_t stream) {
  (void)in_sizes; (void)n_in; (void)out_size; (void)ws_size;
  const int* tokens = (const int*)d_in[0];
  const float* emb = (const float*)d_in[1];
  const float* Wq = (const float*)d_in[2];
  const float* Wk = (const float*)d_in[3];
  const float* Wv = (const float*)d_in[4];
  const float* wq_attn = (const float*)d_in[5];
  const float* wk_attn = (const float*)d_in[6];
  const float* Wr = (const float*)d_in[7];
  const float* br = (const float*)d_in[8];
  const float* Wo = (const float*)d_in[9];
  const float* bo = (const float*)d_in[10];
  const float* Wp = (const float*)d_in[11];
  const float* bp = (const float*)d_in[12];
  const float* Wa = (const float*)d_in[13];
  const float* ba = (const float*)d_in[14];
  const float* va = (const float*)d_in[15];
  unsigned short* wsb = (unsigned short*)d_ws;
  float* out = (float*)d_out;

  prep_weights<<<(PREP_TOTAL + 255) / 256, 256, 0, stream>>>(Wq, Wk, Wv, Wr, Wo, Wp, Wa,
                                                             wq_attn, br, bo, wsb);
  doc_encoder<<<4096, 1024, 0, stream>>>(tokens, emb, wk_attn, bp, ba, va, wsb, out);
}